// Round 1
// baseline (671.509 us; speedup 1.0000x reference)
//
#include <hip/hip_runtime.h>

#define NUM_E 320000
#define NUM_N 10000
#define TILE_M 64   // edges per workgroup

typedef __attribute__((ext_vector_type(8))) short bf16x8;
typedef __attribute__((ext_vector_type(4))) float f32x4;

// RNE fp32 -> bf16 (no NaN handling needed; inputs are finite)
__device__ __forceinline__ short f2bf(float f) {
  unsigned u = __builtin_bit_cast(unsigned, f);
  u += 0x7FFFu + ((u >> 16) & 1u);
  return (short)(u >> 16);
}

// Repack W[k][n] (row-major fp32, 256x256) into B-fragment order bf16:
// Wp[j][s][lane][e] = W[s*32 + (lane>>4)*8 + e][j*16 + (lane&15)]
// j = n-tile (16), s = k-step (8), 64 lanes, 8 elems -> 65536 bf16 per matrix.
__global__ void prep_w(const float* __restrict__ W1, const float* __restrict__ W2,
                       short* __restrict__ Wp) {
  int gid = blockIdx.x * 256 + threadIdx.x;   // 0..16383
  const float* W = (gid & 8192) ? W2 : W1;
  int r = gid & 8191;
  short* dst = Wp + (gid >> 13) * 65536 + r * 8;
  int j = r >> 9;
  int s = (r >> 6) & 7;
  int lane = r & 63;
  int n = j * 16 + (lane & 15);
  int k0 = s * 32 + (lane >> 4) * 8;
  short tmp[8];
#pragma unroll
  for (int e = 0; e < 8; ++e) tmp[e] = f2bf(W[(k0 + e) * 256 + n]);
#pragma unroll
  for (int e = 0; e < 8; ++e) dst[e] = tmp[e];
}

__global__ __launch_bounds__(256, 2) void fused_mlp_scatter(
    const float* __restrict__ X, const int* __restrict__ idx,
    const short* __restrict__ Wp1, const short* __restrict__ Wp2,
    const float* __restrict__ b1, const float* __restrict__ b2,
    float* __restrict__ out, int* __restrict__ cnt) {
  __shared__ short Xl[TILE_M][264];   // +8 pad: row stride 132 dwords == 4 mod 32
  __shared__ int idxl[TILE_M];

  const int tid = threadIdx.x;
  const int wave = tid >> 6;
  const int lane = tid & 63;
  const int q = lane >> 4;     // quad 0..3
  const int m = lane & 15;     // row-in-tile / col-in-tile
  const int row0 = blockIdx.x * TILE_M;

  // ---- stage X tile fp32 -> bf16 into LDS (coalesced float4 reads) ----
  for (int i = tid; i < TILE_M * 64; i += 256) {   // 64 float4 per row
    int r = i >> 6, c4 = i & 63;
    float4 v = reinterpret_cast<const float4*>(X + (size_t)(row0 + r) * 256)[c4];
    unsigned long long packed =
        (unsigned long long)(unsigned short)f2bf(v.x) |
        ((unsigned long long)(unsigned short)f2bf(v.y) << 16) |
        ((unsigned long long)(unsigned short)f2bf(v.z) << 32) |
        ((unsigned long long)(unsigned short)f2bf(v.w) << 48);
    *reinterpret_cast<unsigned long long*>(&Xl[r][c4 * 4]) = packed;
  }
  if (tid < TILE_M) {
    int ix = idx[row0 + tid];
    idxl[tid] = ix;
    atomicAdd(&cnt[ix], 1);
  }
  __syncthreads();

  // ---- layer 1: Y1 = relu(X @ W1 + b1) ----
  f32x4 acc[4][4];
#pragma unroll
  for (int mi = 0; mi < 4; ++mi)
#pragma unroll
    for (int nj = 0; nj < 4; ++nj) acc[mi][nj] = (f32x4)0.0f;

#pragma unroll
  for (int s = 0; s < 8; ++s) {
    bf16x8 a[4], b[4];
#pragma unroll
    for (int mi = 0; mi < 4; ++mi)
      a[mi] = *reinterpret_cast<const bf16x8*>(&Xl[mi * 16 + m][s * 32 + q * 8]);
#pragma unroll
    for (int nj = 0; nj < 4; ++nj)
      b[nj] = *reinterpret_cast<const bf16x8*>(
          Wp1 + (size_t)(((wave * 4 + nj) * 8 + s) * 64 + lane) * 8);
#pragma unroll
    for (int mi = 0; mi < 4; ++mi)
#pragma unroll
      for (int nj = 0; nj < 4; ++nj)
        acc[mi][nj] = __builtin_amdgcn_mfma_f32_16x16x32_bf16(a[mi], b[nj],
                                                              acc[mi][nj], 0, 0, 0);
  }
  __syncthreads();   // done reading X from LDS

  // bias + relu -> bf16 Y1 back into same LDS buffer
  float bias1[4];
#pragma unroll
  for (int nj = 0; nj < 4; ++nj) bias1[nj] = b1[wave * 64 + nj * 16 + m];
#pragma unroll
  for (int mi = 0; mi < 4; ++mi)
#pragma unroll
    for (int nj = 0; nj < 4; ++nj)
#pragma unroll
      for (int r4 = 0; r4 < 4; ++r4) {
        float v = acc[mi][nj][r4] + bias1[nj];
        v = fmaxf(v, 0.0f);
        Xl[mi * 16 + q * 4 + r4][wave * 64 + nj * 16 + m] = f2bf(v);
      }
  __syncthreads();

  // ---- layer 2: Y2 = relu(Y1 @ W2 + b2) ----
#pragma unroll
  for (int mi = 0; mi < 4; ++mi)
#pragma unroll
    for (int nj = 0; nj < 4; ++nj) acc[mi][nj] = (f32x4)0.0f;

#pragma unroll
  for (int s = 0; s < 8; ++s) {
    bf16x8 a[4], b[4];
#pragma unroll
    for (int mi = 0; mi < 4; ++mi)
      a[mi] = *reinterpret_cast<const bf16x8*>(&Xl[mi * 16 + m][s * 32 + q * 8]);
#pragma unroll
    for (int nj = 0; nj < 4; ++nj)
      b[nj] = *reinterpret_cast<const bf16x8*>(
          Wp2 + (size_t)(((wave * 4 + nj) * 8 + s) * 64 + lane) * 8);
#pragma unroll
    for (int mi = 0; mi < 4; ++mi)
#pragma unroll
      for (int nj = 0; nj < 4; ++nj)
        acc[mi][nj] = __builtin_amdgcn_mfma_f32_16x16x32_bf16(a[mi], b[nj],
                                                              acc[mi][nj], 0, 0, 0);
  }

  // ---- epilogue: relu + scatter-add into out ----
  float bias2[4];
#pragma unroll
  for (int nj = 0; nj < 4; ++nj) bias2[nj] = b2[wave * 64 + nj * 16 + m];
#pragma unroll
  for (int mi = 0; mi < 4; ++mi)
#pragma unroll
    for (int r4 = 0; r4 < 4; ++r4) {
      int rr = mi * 16 + q * 4 + r4;
      int node = idxl[rr];
#pragma unroll
      for (int nj = 0; nj < 4; ++nj) {
        int cc = wave * 64 + nj * 16 + m;
        float v = fmaxf(acc[mi][nj][r4] + bias2[nj], 0.0f);
        atomicAdd(&out[node * 256 + cc], v);
      }
    }
}

__global__ void finalize(float* __restrict__ out, const int* __restrict__ cnt) {
  int i = blockIdx.x * 256 + threadIdx.x;   // one float4 per thread
  if (i >= NUM_N * 64) return;
  int n = i >> 6;
  float c = (float)cnt[n];
  float inv = c > 0.0f ? 1.0f / c : 0.0f;
  float4 v = reinterpret_cast<float4*>(out)[i];
  v.x *= inv; v.y *= inv; v.z *= inv; v.w *= inv;
  reinterpret_cast<float4*>(out)[i] = v;
}

extern "C" void kernel_launch(void* const* d_in, const int* in_sizes, int n_in,
                              void* d_out, int out_size, void* d_ws, size_t ws_size,
                              hipStream_t stream) {
  const float* X   = (const float*)d_in[0];
  const int*   idx = (const int*)d_in[1];
  // d_in[2] = dim_size scalar (fixed at NUM_N)
  const float* W1  = (const float*)d_in[3];
  const float* b1  = (const float*)d_in[4];
  const float* W2  = (const float*)d_in[5];
  const float* b2  = (const float*)d_in[6];
  float* out = (float*)d_out;

  short* Wp  = (short*)d_ws;                          // 2 * 65536 bf16 = 256 KB
  int*   cnt = (int*)((char*)d_ws + 2 * 65536 * 2);   // 40 KB

  hipMemsetAsync(out, 0, (size_t)NUM_N * 256 * sizeof(float), stream);
  hipMemsetAsync(cnt, 0, NUM_N * sizeof(int), stream);

  prep_w<<<64, 256, 0, stream>>>(W1, W2, Wp);
  fused_mlp_scatter<<<NUM_E / TILE_M, 256, 0, stream>>>(
      X, idx, Wp, Wp + 65536, b1, b2, out, cnt);
  finalize<<<(NUM_N * 64 + 255) / 256, 256, 0, stream>>>(out, cnt);
}

// Round 2
// 664.962 us; speedup vs baseline: 1.0098x; 1.0098x over previous
//
#include <hip/hip_runtime.h>

#define NUM_E 320000
#define NUM_N 10000

typedef __attribute__((ext_vector_type(8))) short bf16x8;
typedef __attribute__((ext_vector_type(4))) float f32x4;

// RNE fp32 -> bf16
__device__ __forceinline__ short f2bf(float f) {
  unsigned u = __builtin_bit_cast(unsigned, f);
  u += 0x7FFFu + ((u >> 16) & 1u);
  return (short)(u >> 16);
}

// Repack W[k][n] (row-major fp32 256x256) into B-fragment order bf16.
__global__ void prep_w(const float* __restrict__ W1, const float* __restrict__ W2,
                       short* __restrict__ Wp) {
  int gid = blockIdx.x * 256 + threadIdx.x;   // 0..16383
  const float* W = (gid & 8192) ? W2 : W1;
  int r = gid & 8191;
  short* dst = Wp + (gid >> 13) * 65536 + r * 8;
  int j = r >> 9;
  int s = (r >> 6) & 7;
  int lane = r & 63;
  int n = j * 16 + (lane & 15);
  int k0 = s * 32 + (lane >> 4) * 8;
  short tmp[8];
#pragma unroll
  for (int e = 0; e < 8; ++e) tmp[e] = f2bf(W[(k0 + e) * 256 + n]);
#pragma unroll
  for (int e = 0; e < 8; ++e) dst[e] = tmp[e];
}

// ---- counting sort of edges by target node ----
__global__ void hist_k(const int* __restrict__ idx, int* __restrict__ cnt) {
  int e = blockIdx.x * 256 + threadIdx.x;
  if (e < NUM_E) atomicAdd(&cnt[idx[e]], 1);
}

// single block: exclusive prefix sum of cnt -> fill (start offsets), inv = 1/cnt
__global__ void scan_k(const int* __restrict__ cnt, int* __restrict__ fill,
                       float* __restrict__ inv) {
  __shared__ int part[256];
  int t = threadIdx.x;
  int base = t * 40;
  int local[40];
  int s = 0;
#pragma unroll
  for (int i = 0; i < 40; ++i) {
    int n = base + i;
    int c = (n < NUM_N) ? cnt[n] : 0;
    local[i] = s;
    s += c;
  }
  part[t] = s;
  __syncthreads();
  for (int off = 1; off < 256; off <<= 1) {
    int tmp = 0;
    if (t >= off) tmp = part[t - off];
    __syncthreads();
    if (t >= off) part[t] += tmp;
    __syncthreads();
  }
  int ebase = (t == 0) ? 0 : part[t - 1];
#pragma unroll
  for (int i = 0; i < 40; ++i) {
    int n = base + i;
    if (n < NUM_N) {
      fill[n] = ebase + local[i];
      int c = cnt[n];
      inv[n] = (c > 0) ? 1.0f / (float)c : 0.0f;
    }
  }
}

__global__ void scatter_k(const int* __restrict__ idx, int* __restrict__ fill,
                          int* __restrict__ sorted) {
  int e = blockIdx.x * 256 + threadIdx.x;
  if (e < NUM_E) {
    int ix = idx[e];
    int pos = atomicAdd(&fill[ix], 1);
    sorted[pos] = e;
  }
}

// ---- fused MLP over 64 sorted edges + segmented scatter-mean ----
__global__ __launch_bounds__(256, 2) void fused_mlp_gather(
    const float* __restrict__ X, const int* __restrict__ idx,
    const int* __restrict__ sorted,
    const short* __restrict__ Wp1, const short* __restrict__ Wp2,
    const float* __restrict__ b1, const float* __restrict__ b2,
    const float* __restrict__ inv, float* __restrict__ out) {
  __shared__ __align__(16) float smem[64 * 260];   // 66560 B, overlaid
  short (*Xl)[264] = reinterpret_cast<short(*)[264]>(smem);   // bf16 X / Y1
  float (*Yout)[260] = reinterpret_cast<float(*)[260]>(smem); // fp32 Y2
  __shared__ int idxl[64];
  __shared__ int se[64];

  const int tid = threadIdx.x;
  const int wave = tid >> 6;
  const int lane = tid & 63;
  const int q = lane >> 4;
  const int m = lane & 15;
  const int row0 = blockIdx.x * 64;

  if (tid < 64) {
    int e = sorted[row0 + tid];
    se[tid] = e;
    idxl[tid] = idx[e];
  }
  __syncthreads();

  // stage gathered X rows fp32 -> bf16 (each row read 1KB-contiguous)
  for (int i = tid; i < 64 * 64; i += 256) {
    int r = i >> 6, c4 = i & 63;
    float4 v = reinterpret_cast<const float4*>(X + (size_t)se[r] * 256)[c4];
    unsigned long long packed =
        (unsigned long long)(unsigned short)f2bf(v.x) |
        ((unsigned long long)(unsigned short)f2bf(v.y) << 16) |
        ((unsigned long long)(unsigned short)f2bf(v.z) << 32) |
        ((unsigned long long)(unsigned short)f2bf(v.w) << 48);
    *reinterpret_cast<unsigned long long*>(&Xl[r][c4 * 4]) = packed;
  }
  __syncthreads();

  // ---- layer 1 ----
  f32x4 acc[4][4];
#pragma unroll
  for (int mi = 0; mi < 4; ++mi)
#pragma unroll
    for (int nj = 0; nj < 4; ++nj) acc[mi][nj] = (f32x4)0.0f;

#pragma unroll
  for (int s = 0; s < 8; ++s) {
    bf16x8 a[4], b[4];
#pragma unroll
    for (int mi = 0; mi < 4; ++mi)
      a[mi] = *reinterpret_cast<const bf16x8*>(&Xl[mi * 16 + m][s * 32 + q * 8]);
#pragma unroll
    for (int nj = 0; nj < 4; ++nj)
      b[nj] = *reinterpret_cast<const bf16x8*>(
          Wp1 + (size_t)(((wave * 4 + nj) * 8 + s) * 64 + lane) * 8);
#pragma unroll
    for (int mi = 0; mi < 4; ++mi)
#pragma unroll
      for (int nj = 0; nj < 4; ++nj)
        acc[mi][nj] = __builtin_amdgcn_mfma_f32_16x16x32_bf16(a[mi], b[nj],
                                                              acc[mi][nj], 0, 0, 0);
  }
  __syncthreads();   // done reading X

  float bias1[4];
#pragma unroll
  for (int nj = 0; nj < 4; ++nj) bias1[nj] = b1[wave * 64 + nj * 16 + m];
#pragma unroll
  for (int mi = 0; mi < 4; ++mi)
#pragma unroll
    for (int nj = 0; nj < 4; ++nj)
#pragma unroll
      for (int r4 = 0; r4 < 4; ++r4) {
        float v = fmaxf(acc[mi][nj][r4] + bias1[nj], 0.0f);
        Xl[mi * 16 + q * 4 + r4][wave * 64 + nj * 16 + m] = f2bf(v);
      }
  __syncthreads();

  // ---- layer 2 ----
#pragma unroll
  for (int mi = 0; mi < 4; ++mi)
#pragma unroll
    for (int nj = 0; nj < 4; ++nj) acc[mi][nj] = (f32x4)0.0f;

#pragma unroll
  for (int s = 0; s < 8; ++s) {
    bf16x8 a[4], b[4];
#pragma unroll
    for (int mi = 0; mi < 4; ++mi)
      a[mi] = *reinterpret_cast<const bf16x8*>(&Xl[mi * 16 + m][s * 32 + q * 8]);
#pragma unroll
    for (int nj = 0; nj < 4; ++nj)
      b[nj] = *reinterpret_cast<const bf16x8*>(
          Wp2 + (size_t)(((wave * 4 + nj) * 8 + s) * 64 + lane) * 8);
#pragma unroll
    for (int mi = 0; mi < 4; ++mi)
#pragma unroll
      for (int nj = 0; nj < 4; ++nj)
        acc[mi][nj] = __builtin_amdgcn_mfma_f32_16x16x32_bf16(a[mi], b[nj],
                                                              acc[mi][nj], 0, 0, 0);
  }
  __syncthreads();   // all Y1 reads done before smem becomes fp32 Y2

  float bias2[4];
#pragma unroll
  for (int nj = 0; nj < 4; ++nj) bias2[nj] = b2[wave * 64 + nj * 16 + m];
#pragma unroll
  for (int mi = 0; mi < 4; ++mi)
#pragma unroll
    for (int nj = 0; nj < 4; ++nj)
#pragma unroll
      for (int r4 = 0; r4 < 4; ++r4)
        Yout[mi * 16 + q * 4 + r4][wave * 64 + nj * 16 + m] =
            fmaxf(acc[mi][nj][r4] + bias2[nj], 0.0f);
  __syncthreads();

  // ---- segmented reduce: thread tid = column, rows sorted by node ----
  float run = 0.0f;
  int prev = idxl[0];
  for (int r = 0; r < 64; ++r) {
    int node = idxl[r];             // block-uniform -> uniform branch
    if (node != prev) {
      if (run != 0.0f) atomicAdd(&out[(size_t)prev * 256 + tid], run * inv[prev]);
      run = 0.0f;
      prev = node;
    }
    run += Yout[r][tid];
  }
  if (run != 0.0f) atomicAdd(&out[(size_t)prev * 256 + tid], run * inv[prev]);
}

extern "C" void kernel_launch(void* const* d_in, const int* in_sizes, int n_in,
                              void* d_out, int out_size, void* d_ws, size_t ws_size,
                              hipStream_t stream) {
  const float* X   = (const float*)d_in[0];
  const int*   idx = (const int*)d_in[1];
  const float* W1  = (const float*)d_in[3];
  const float* b1  = (const float*)d_in[4];
  const float* W2  = (const float*)d_in[5];
  const float* b2  = (const float*)d_in[6];
  float* out = (float*)d_out;

  char* ws = (char*)d_ws;
  short* Wp     = (short*)(ws);                 // 262144 B
  int*   cnt    = (int*)(ws + 262144);          // 40960 B
  int*   fill   = (int*)(ws + 303104);          // 40960 B
  float* inv    = (float*)(ws + 344064);        // 40960 B
  int*   sorted = (int*)(ws + 385024);          // 1280000 B

  hipMemsetAsync(out, 0, (size_t)NUM_N * 256 * sizeof(float), stream);
  hipMemsetAsync(cnt, 0, NUM_N * sizeof(int), stream);

  prep_w<<<64, 256, 0, stream>>>(W1, W2, Wp);
  hist_k<<<(NUM_E + 255) / 256, 256, 0, stream>>>(idx, cnt);
  scan_k<<<1, 256, 0, stream>>>(cnt, fill, inv);
  scatter_k<<<(NUM_E + 255) / 256, 256, 0, stream>>>(idx, fill, sorted);
  fused_mlp_gather<<<NUM_E / 64, 256, 0, stream>>>(
      X, idx, sorted, Wp, Wp + 65536, b1, b2, inv, out);
}

// Round 3
// 586.724 us; speedup vs baseline: 1.1445x; 1.1333x over previous
//
#include <hip/hip_runtime.h>

#define NUM_E 320000
#define NUM_N 10000

typedef __attribute__((ext_vector_type(8))) short bf16x8;
typedef __attribute__((ext_vector_type(4))) float f32x4;

// RNE fp32 -> bf16
__device__ __forceinline__ short f2bf(float f) {
  unsigned u = __builtin_bit_cast(unsigned, f);
  u += 0x7FFFu + ((u >> 16) & 1u);
  return (short)(u >> 16);
}

// ---- combo: zero(out) [blocks 0..639] + hist [640..1889] + prep_w [1890..1953] ----
__global__ void combo_k(const float* __restrict__ W1, const float* __restrict__ W2,
                        short* __restrict__ Wp, const int* __restrict__ idx,
                        int* __restrict__ cnt, float* __restrict__ out) {
  int b = blockIdx.x;
  int t = threadIdx.x;
  if (b < 640) {
    // zero out: 2,560,000 floats = 640,000 float4
    int base = b * 256 + t;
#pragma unroll
    for (int k = 0; k < 4; ++k) {
      int f4 = base + k * 163840;
      if (f4 < 640000) reinterpret_cast<float4*>(out)[f4] = make_float4(0, 0, 0, 0);
    }
  } else if (b < 1890) {
    int e = (b - 640) * 256 + t;
    if (e < NUM_E) atomicAdd(&cnt[idx[e]], 1);
  } else {
    // weight repack: W[k][n] fp32 -> B-fragment bf16
    int gid = (b - 1890) * 256 + t;           // 0..16383
    const float* W = (gid & 8192) ? W2 : W1;
    int r = gid & 8191;
    short* dst = Wp + (gid >> 13) * 65536 + r * 8;
    int j = r >> 9;
    int s = (r >> 6) & 7;
    int lane = r & 63;
    int n = j * 16 + (lane & 15);
    int k0 = s * 32 + (lane >> 4) * 8;
    short tmp[8];
#pragma unroll
    for (int e = 0; e < 8; ++e) tmp[e] = f2bf(W[(k0 + e) * 256 + n]);
#pragma unroll
    for (int e = 0; e < 8; ++e) dst[e] = tmp[e];
  }
}

// single block: exclusive prefix sum of cnt -> fill (start offsets), inv = 1/cnt
__global__ void scan_k(const int* __restrict__ cnt, int* __restrict__ fill,
                       float* __restrict__ inv) {
  __shared__ int part[256];
  int t = threadIdx.x;
  int base = t * 40;
  int local[40];
  int s = 0;
#pragma unroll
  for (int i = 0; i < 40; ++i) {
    int n = base + i;
    int c = (n < NUM_N) ? cnt[n] : 0;
    local[i] = s;
    s += c;
  }
  part[t] = s;
  __syncthreads();
  for (int off = 1; off < 256; off <<= 1) {
    int tmp = 0;
    if (t >= off) tmp = part[t - off];
    __syncthreads();
    if (t >= off) part[t] += tmp;
    __syncthreads();
  }
  int ebase = (t == 0) ? 0 : part[t - 1];
#pragma unroll
  for (int i = 0; i < 40; ++i) {
    int n = base + i;
    if (n < NUM_N) {
      fill[n] = ebase + local[i];
      int c = cnt[n];
      inv[n] = (c > 0) ? 1.0f / (float)c : 0.0f;
    }
  }
}

__global__ void scatter_k(const int* __restrict__ idx, int* __restrict__ fill,
                          int* __restrict__ sorted) {
  int e = blockIdx.x * 256 + threadIdx.x;
  if (e < NUM_E) {
    int ix = idx[e];
    int pos = atomicAdd(&fill[ix], 1);
    sorted[pos] = e;
  }
}

// ---- fused MLP over 64 sorted edges + in-register segmented scatter-mean ----
__global__ __launch_bounds__(256, 4) void fused_mlp_gather(
    const float* __restrict__ X, const int* __restrict__ idx,
    const int* __restrict__ sorted,
    const short* __restrict__ Wp1, const short* __restrict__ Wp2,
    const float* __restrict__ b1, const float* __restrict__ b2,
    const float* __restrict__ inv, float* __restrict__ out) {
  __shared__ __align__(16) short Xl[64][264];   // bf16 X, then Y1 (33792 B)
  __shared__ int idxl[64];
  __shared__ int se[64];
  __shared__ int segLo[64];
  __shared__ int segN[64];
  __shared__ int nsegS;

  const int tid = threadIdx.x;
  const int wave = tid >> 6;
  const int lane = tid & 63;
  const int q = lane >> 4;
  const int m = lane & 15;
  const int row0 = blockIdx.x * 64;

  if (tid < 64) {
    int e = sorted[row0 + tid];
    se[tid] = e;
    idxl[tid] = idx[e];
  }
  __syncthreads();

  // stage gathered X rows fp32 -> bf16 into LDS
  for (int i = tid; i < 64 * 64; i += 256) {
    int r = i >> 6, c4 = i & 63;
    float4 v = reinterpret_cast<const float4*>(X + (size_t)se[r] * 256)[c4];
    unsigned long long packed =
        (unsigned long long)(unsigned short)f2bf(v.x) |
        ((unsigned long long)(unsigned short)f2bf(v.y) << 16) |
        ((unsigned long long)(unsigned short)f2bf(v.z) << 32) |
        ((unsigned long long)(unsigned short)f2bf(v.w) << 48);
    *reinterpret_cast<unsigned long long*>(&Xl[r][c4 * 4]) = packed;
  }
  __syncthreads();

  // segment list (runs in sorted idxl) — wave 0; visible after next barrier
  if (wave == 0) {
    bool flag = (lane == 0) || (idxl[lane] != idxl[lane - 1]);
    unsigned long long mask = __ballot(flag);
    if (lane == 0) nsegS = (int)__popcll(mask);
    if (flag) {
      int sidx = (int)__popcll(mask & ((1ull << lane) - 1ull));
      segLo[sidx] = lane;
      segN[sidx] = idxl[lane];
    }
  }

  // ---- layer 1 ----
  f32x4 acc[4][4];
#pragma unroll
  for (int mi = 0; mi < 4; ++mi)
#pragma unroll
    for (int nj = 0; nj < 4; ++nj) acc[mi][nj] = (f32x4)0.0f;

#pragma unroll
  for (int s = 0; s < 8; ++s) {
    bf16x8 a[4], b[4];
#pragma unroll
    for (int mi = 0; mi < 4; ++mi)
      a[mi] = *reinterpret_cast<const bf16x8*>(&Xl[mi * 16 + m][s * 32 + q * 8]);
#pragma unroll
    for (int nj = 0; nj < 4; ++nj)
      b[nj] = *reinterpret_cast<const bf16x8*>(
          Wp1 + (size_t)(((wave * 4 + nj) * 8 + s) * 64 + lane) * 8);
#pragma unroll
    for (int mi = 0; mi < 4; ++mi)
#pragma unroll
      for (int nj = 0; nj < 4; ++nj)
        acc[mi][nj] = __builtin_amdgcn_mfma_f32_16x16x32_bf16(a[mi], b[nj],
                                                              acc[mi][nj], 0, 0, 0);
  }
  __syncthreads();   // done reading X

  float bias1[4];
#pragma unroll
  for (int nj = 0; nj < 4; ++nj) bias1[nj] = b1[wave * 64 + nj * 16 + m];
#pragma unroll
  for (int mi = 0; mi < 4; ++mi)
#pragma unroll
    for (int nj = 0; nj < 4; ++nj)
#pragma unroll
      for (int r4 = 0; r4 < 4; ++r4) {
        float v = fmaxf(acc[mi][nj][r4] + bias1[nj], 0.0f);
        Xl[mi * 16 + q * 4 + r4][wave * 64 + nj * 16 + m] = f2bf(v);
      }
  __syncthreads();

  // ---- layer 2 ----
#pragma unroll
  for (int mi = 0; mi < 4; ++mi)
#pragma unroll
    for (int nj = 0; nj < 4; ++nj) acc[mi][nj] = (f32x4)0.0f;

#pragma unroll
  for (int s = 0; s < 8; ++s) {
    bf16x8 a[4], b[4];
#pragma unroll
    for (int mi = 0; mi < 4; ++mi)
      a[mi] = *reinterpret_cast<const bf16x8*>(&Xl[mi * 16 + m][s * 32 + q * 8]);
#pragma unroll
    for (int nj = 0; nj < 4; ++nj)
      b[nj] = *reinterpret_cast<const bf16x8*>(
          Wp2 + (size_t)(((wave * 4 + nj) * 8 + s) * 64 + lane) * 8);
#pragma unroll
    for (int mi = 0; mi < 4; ++mi)
#pragma unroll
      for (int nj = 0; nj < 4; ++nj)
        acc[mi][nj] = __builtin_amdgcn_mfma_f32_16x16x32_bf16(a[mi], b[nj],
                                                              acc[mi][nj], 0, 0, 0);
  }

  // bias2 + relu in-register
  float bias2[4];
#pragma unroll
  for (int nj = 0; nj < 4; ++nj) bias2[nj] = b2[wave * 64 + nj * 16 + m];
#pragma unroll
  for (int mi = 0; mi < 4; ++mi)
#pragma unroll
    for (int nj = 0; nj < 4; ++nj)
#pragma unroll
      for (int r4 = 0; r4 < 4; ++r4)
        acc[mi][nj][r4] = fmaxf(acc[mi][nj][r4] + bias2[nj], 0.0f);

  // ---- in-register segmented reduce + scatter ----
  // value acc[mi][nj][r4] is Y2[row=mi*16+q*4+r4][col=wave*64+nj*16+m]
  int nseg = nsegS;
  for (int s = 0; s < nseg; ++s) {
    int lo = segLo[s];
    int hi = (s + 1 < nseg) ? segLo[s + 1] : 64;
    int node = segN[s];
    float sum[4] = {0.0f, 0.0f, 0.0f, 0.0f};
#pragma unroll
    for (int mi = 0; mi < 4; ++mi)
#pragma unroll
      for (int r4 = 0; r4 < 4; ++r4) {
        int row = mi * 16 + q * 4 + r4;
        float msk = (row >= lo && row < hi) ? 1.0f : 0.0f;
#pragma unroll
        for (int nj = 0; nj < 4; ++nj) sum[nj] = fmaf(msk, acc[mi][nj][r4], sum[nj]);
      }
    float scale = inv[node];
#pragma unroll
    for (int nj = 0; nj < 4; ++nj) {
      float v = sum[nj];
      v += __shfl_xor(v, 16, 64);
      v += __shfl_xor(v, 32, 64);
      if (q == 0 && v != 0.0f)
        atomicAdd(&out[(size_t)node * 256 + wave * 64 + nj * 16 + m], v * scale);
    }
  }
}

extern "C" void kernel_launch(void* const* d_in, const int* in_sizes, int n_in,
                              void* d_out, int out_size, void* d_ws, size_t ws_size,
                              hipStream_t stream) {
  const float* X   = (const float*)d_in[0];
  const int*   idx = (const int*)d_in[1];
  const float* W1  = (const float*)d_in[3];
  const float* b1  = (const float*)d_in[4];
  const float* W2  = (const float*)d_in[5];
  const float* b2  = (const float*)d_in[6];
  float* out = (float*)d_out;

  char* ws = (char*)d_ws;
  short* Wp     = (short*)(ws);                 // 262144 B
  int*   cnt    = (int*)(ws + 262144);          // 40960 B
  int*   fill   = (int*)(ws + 303104);          // 40960 B
  float* inv    = (float*)(ws + 344064);        // 40960 B
  int*   sorted = (int*)(ws + 385024);          // 1280000 B

  hipMemsetAsync(cnt, 0, NUM_N * sizeof(int), stream);
  combo_k<<<1954, 256, 0, stream>>>(W1, W2, Wp, idx, cnt, out);
  scan_k<<<1, 256, 0, stream>>>(cnt, fill, inv);
  scatter_k<<<(NUM_E + 255) / 256, 256, 0, stream>>>(idx, fill, sorted);
  fused_mlp_gather<<<NUM_E / 64, 256, 0, stream>>>(
      X, idx, sorted, Wp, Wp + 65536, b1, b2, inv, out);
}